// Round 15
// baseline (277.569 us; speedup 1.0000x reference)
//
#include <hip/hip_runtime.h>
#include <hip/hip_bf16.h>

constexpr int BATCH = 32768;
constexpr int KDIM  = 128;    // IN_F
constexpr int NDIM  = 2048;   // OUT_F

using f32x4  = __attribute__((ext_vector_type(4))) float;
using bf16x8 = __attribute__((ext_vector_type(8))) short;

// ---------------------------------------------------------------------------
// Fragment order for mfma_f32_16x16x32_bf16 (verified R2/R3):
//   A (MxK): lane l holds m = l&15,  k(j) = 4*(l>>4) + (j&3) + 16*(j>>2)
//   B (KxN): lane l holds n = l&15,  same k(j)
//   D:       lane l holds col = l&15, row = (l>>4)*4 + reg
// 2-term split: z = (x_hi + x_lo) @ W_hi  (absmax ~8e-3 < 2e-2 threshold)
//
// R15: the wall (R8..R14 all 210-225us) is latency exposure: per-block time
// 56us vs ~6us of pipe work; HBM has nothing in flight during GEMM/solve.
// Fix: 256 PERSISTENT blocks (1/CU), 8 tiles each; stage the whole 128KB pm
// tile to LDS via global_load_lds (zero VGPR), issued after the LAST barrier
// of the previous tile so the transfer overlaps store+A-loads+GEMM. 128KB
// outstanding per CU >> Little's-law 16KB -> HBM-paced, not latency-paced.
// Swapped-operand GEMM (R9/R12: lane owns row, aligned pm/out). pm LDS pitch
// 2052 -> conflict-free b128 gate reads. R12 compacted Michelot (proven).
// ---------------------------------------------------------------------------

#define GLOBAL_TO_LDS16(gsrc, ldst)                                          \
    __builtin_amdgcn_global_load_lds(                                        \
        (const __attribute__((address_space(1))) unsigned int*)(gsrc),       \
        (__attribute__((address_space(3))) unsigned int*)(ldst), 16, 0, 0)

__device__ inline void split_bf16(float v, ushort& hi, ushort& lo) {
    __hip_bfloat16 h = __float2bfloat16(v);
    float r = v - __bfloat162float(h);
    __hip_bfloat16 l = __float2bfloat16(r);
    hi = *reinterpret_cast<ushort*>(&h);
    lo = *reinterpret_cast<ushort*>(&l);
}

// W [128][2048] -> Bh[nt=128][kk=4][lane=64][j=8]  (hi only)
__global__ __launch_bounds__(256)
void conv_w_kernel(const float* __restrict__ W, ushort* __restrict__ Bh) {
    int id = blockIdx.x * 256 + threadIdx.x;      // 0 .. 262143
    int j  = id & 7;
    int l  = (id >> 3) & 63;
    int kk = (id >> 9) & 3;
    int nt = id >> 11;
    int k  = kk * 32 + 4 * (l >> 4) + (j & 3) + 16 * (j >> 2);
    int n  = nt * 16 + (l & 15);
    __hip_bfloat16 h = __float2bfloat16(W[k * NDIM + n]);
    Bh[id] = *reinterpret_cast<ushort*>(&h);
}

// x [32768][128] -> A{h,l}[rt=2048][kk=4][lane=64][j=8]
__global__ __launch_bounds__(256)
void conv_x_kernel(const float* __restrict__ x,
                   ushort* __restrict__ Ah, ushort* __restrict__ Al) {
    int id = blockIdx.x * 256 + threadIdx.x;      // 0 .. 4194303
    int j  = id & 7;
    int l  = (id >> 3) & 63;
    int kk = (id >> 9) & 3;
    int rt = id >> 11;
    int k  = kk * 32 + 4 * (l >> 4) + (j & 3) + 16 * (j >> 2);
    int m  = rt * 16 + (l & 15);
    ushort hi, lo;
    split_bf16(x[m * KDIM + k], hi, lo);
    Ah[id] = hi; Al[id] = lo;
}

// ---------------------------------------------------------------------------
// Main: 256 persistent blocks, 512 thr (8 waves), 8 tiles of 16 rows each.
// Wave q: col tiles q*16+t (swapped MFMA); lane l owns row l&15,
// cols {q*256 + t*16 + (l>>4)*4 + r}.
// ---------------------------------------------------------------------------
constexpr int GRID  = 256;
constexpr int TILES = BATCH / 16 / GRID;        // 8
constexpr int CAP   = 128;
constexpr int PMP   = 2052;                     // pm LDS pitch (floats)
constexpr int PMLDS_BYTES = 16 * PMP * 4;       // 131328 B dynamic

__global__ __launch_bounds__(512, 2)
void mfma_sparsemax_persistent(const ushort* __restrict__ Ah, const ushort* __restrict__ Al,
                               const ushort* __restrict__ Bh,
                               const float* __restrict__ pm, float* __restrict__ out) {
    extern __shared__ float pmlds[];            // [16][PMP]
    __shared__ float2 red[2][8][16];            // 2 KB
    __shared__ float  cand[16][CAP];            // 8 KB
    __shared__ int    cnt[16];
    __shared__ float  taus0[16];
    __shared__ float  taus[16];

    const int tid = threadIdx.x;
    const int l   = tid & 63;
    const int q   = tid >> 6;                   // wave id 0..7
    const int g   = l >> 4;
    const int m0  = l & 15;                     // my batch row (local)

    const bf16x8* A8h = reinterpret_cast<const bf16x8*>(Ah);
    const bf16x8* A8l = reinterpret_cast<const bf16x8*>(Al);
    const bf16x8* B8h = reinterpret_cast<const bf16x8*>(Bh);

    // ---- stage tile 0's pm (wave q -> rows 2q, 2q+1) ----
    {
        const int rt0 = blockIdx.x * TILES;
        #pragma unroll
        for (int i = 0; i < 16; ++i) {
            const int row = 2 * q + (i >> 3);
            const int ch  = i & 7;
            GLOBAL_TO_LDS16(pm + ((long)rt0 * 16 + row) * NDIM + ch * 256 + l * 4,
                            pmlds + row * PMP + ch * 256);
        }
    }

    for (int it = 0; it < TILES; ++it) {
        const int rt   = blockIdx.x * TILES + it;
        const long grow = (long)rt * 16 + m0;

        // ---- A fragments ----
        bf16x8 ah[4], al4[4];
        #pragma unroll
        for (int kk = 0; kk < 4; ++kk) {
            ah[kk]  = A8h[(rt * 4 + kk) * 64 + l];
            al4[kk] = A8l[(rt * 4 + kk) * 64 + l];
        }

        // ---- GEMM, swapped: acc[t] = z[grow][q*256 + t*16 + g*4 .. +3] ----
        f32x4 acc[16];
        #pragma unroll
        for (int t = 0; t < 16; ++t) {
            const int nt = q * 16 + t;
            f32x4 c = {0.f, 0.f, 0.f, 0.f};
            #pragma unroll
            for (int kk = 0; kk < 4; ++kk) {
                bf16x8 b = B8h[(nt * 4 + kk) * 64 + l];
                c = __builtin_amdgcn_mfma_f32_16x16x32_bf16(b, ah[kk],  c, 0, 0, 0);
                c = __builtin_amdgcn_mfma_f32_16x16x32_bf16(b, al4[kk], c, 0, 0, 0);
            }
            acc[t] = c;
        }

        __syncthreads();                        // [T] pm stage for tile it complete

        // ---- gate from LDS (conflict-free: 8-lane groups span bank quartets)
        const float* myrow = pmlds + m0 * PMP + q * 256 + g * 4;
        #pragma unroll
        for (int t = 0; t < 16; ++t)
            acc[t] *= *reinterpret_cast<const f32x4*>(myrow + t * 16);

        // ---- row max & sum -> tau0 ----
        float mx = acc[0][0], sm = 0.f;
        #pragma unroll
        for (int t = 0; t < 16; ++t)
            #pragma unroll
            for (int r = 0; r < 4; ++r) { float v = acc[t][r]; mx = fmaxf(mx, v); sm += v; }
        mx = fmaxf(mx, __shfl_xor(mx, 16, 64));
        mx = fmaxf(mx, __shfl_xor(mx, 32, 64));
        sm += __shfl_xor(sm, 16, 64);
        sm += __shfl_xor(sm, 32, 64);
        if (l < 16) red[0][q][l] = make_float2(mx, sm);
        if (tid < 16) cnt[tid] = 0;
        __syncthreads();                        // [B1]
        float M = -1e30f, S = 0.f;
        #pragma unroll
        for (int w = 0; w < 8; ++w) { float2 e = red[0][w][m0]; M = fmaxf(M, e.x); S += e.y; }
        const float tau0 = fmaxf(M - 1.f, (S - 1.f) * (1.f / 2048.f));
        if (tid < 16) taus0[tid] = tau0;

        // ---- push candidates (v > tau0, own row) ----
        #pragma unroll
        for (int t = 0; t < 16; ++t)
            #pragma unroll
            for (int r = 0; r < 4; ++r) {
                float v = acc[t][r];
                if (v > tau0) {
                    int idx = atomicAdd(&cnt[m0], 1);
                    if (idx < CAP) cand[m0][idx] = v;
                }
            }
        __syncthreads();                        // [B2]
        const bool ovf = __syncthreads_or((tid < 16) && (cnt[tid] > CAP));  // [B3]

        if (!ovf) {
            // ---- wave-local Michelot: half-wave (q,sub) owns row 2q+sub ----
            const int sub    = l >> 5;
            const int lane32 = l & 31;
            const int row    = 2 * q + sub;
            const int n      = cnt[row];
            float cv[4];
            #pragma unroll
            for (int j = 0; j < 4; ++j) {
                int idx = lane32 + 32 * j;
                cv[j] = (idx < n) ? cand[row][idx] : -1e30f;
            }
            float tau = taus0[row], cprev = -1.f;
            for (int s = 0; s < 64; ++s) {
                float ps = 0.f, pc = 0.f;
                #pragma unroll
                for (int j = 0; j < 4; ++j) {
                    bool a = cv[j] > tau;
                    ps += a ? cv[j] : 0.f;
                    pc += a ? 1.f : 0.f;
                }
                #pragma unroll
                for (int off = 1; off < 32; off <<= 1) {
                    ps += __shfl_xor(ps, off, 64);
                    pc += __shfl_xor(pc, off, 64);
                }
                tau = (ps - 1.f) / pc;          // pc >= 1 (rowmax > tau0)
                bool done = (pc == cprev);
                cprev = pc;
                if (__all(done)) break;
            }
            if (lane32 == 0) taus[row] = tau;
        } else {
            // ---- fallback: block-wide Michelot (degenerate rows) ----
            float tau = tau0, cprev = -1.f;
            for (int s = 0; s < 32; ++s) {
                float ps = 0.f, pc = 0.f;
                #pragma unroll
                for (int t = 0; t < 16; ++t)
                    #pragma unroll
                    for (int r = 0; r < 4; ++r) {
                        float v = acc[t][r];
                        bool a = v > tau;
                        ps += a ? v : 0.f;
                        pc += a ? 1.f : 0.f;
                    }
                ps += __shfl_xor(ps, 16, 64);
                ps += __shfl_xor(ps, 32, 64);
                pc += __shfl_xor(pc, 16, 64);
                pc += __shfl_xor(pc, 32, 64);
                const int buf = (s + 1) & 1;
                if (l < 16) red[buf][q][l] = make_float2(ps, pc);
                __syncthreads();
                float SS = 0.f, CC = 0.f;
                #pragma unroll
                for (int w = 0; w < 8; ++w) { float2 e = red[buf][w][m0]; SS += e.x; CC += e.y; }
                tau = (SS - 1.f) / CC;
                int done = (CC == cprev);
                cprev = CC;
                if (__syncthreads_and(done)) break;
            }
            if (tid < 16) taus[m0] = tau;
        }
        __syncthreads();                        // [B4] taus ready; pmlds reads long done
        const float mytau = taus[m0];

        // ---- stage NEXT tile's pm now: overlaps store + A-loads + GEMM ----
        if (it + 1 < TILES) {
            const int rtn = rt + 1;
            #pragma unroll
            for (int i = 0; i < 16; ++i) {
                const int row = 2 * q + (i >> 3);
                const int ch  = i & 7;
                GLOBAL_TO_LDS16(pm + ((long)rtn * 16 + row) * NDIM + ch * 256 + l * 4,
                                pmlds + row * PMP + ch * 256);
            }
        }

        // ---- out = max(z - tau, 0): per-lane aligned f32x4 stores ----
        float* obase = out + grow * NDIM + q * 256 + g * 4;
        #pragma unroll
        for (int t = 0; t < 16; ++t) {
            f32x4 v = acc[t];
            f32x4 o;
            o.x = fmaxf(v.x - mytau, 0.f);
            o.y = fmaxf(v.y - mytau, 0.f);
            o.z = fmaxf(v.z - mytau, 0.f);
            o.w = fmaxf(v.w - mytau, 0.f);
            *reinterpret_cast<f32x4*>(obase + t * 16) = o;
        }
    }
}

// ---------------------------------------------------------------------------
// Fallback (R1 kernel) if d_ws too small.
// ---------------------------------------------------------------------------
__device__ inline float wave_sum(float v) {
    #pragma unroll
    for (int off = 32; off > 0; off >>= 1) v += __shfl_xor(v, off, 64);
    return v;
}

__global__ __launch_bounds__(256)
void fused_sparsemax_fallback(const float* __restrict__ x,
                              const float* __restrict__ pm,
                              const float* __restrict__ W,
                              float* __restrict__ out) {
    __shared__ float xs[8][KDIM];
    __shared__ float zsf[4][NDIM];
    const int tid  = threadIdx.x;
    const int lane = tid & 63;
    const int wv   = tid >> 6;
    const long r0  = (long)blockIdx.x * 8;
    {
        const float4* src = reinterpret_cast<const float4*>(x + r0 * KDIM);
        reinterpret_cast<float4*>(&xs[0][0])[tid] = src[tid];
    }
    __syncthreads();
    float acc[8][8];
    #pragma unroll
    for (int r = 0; r < 8; ++r)
        #pragma unroll
        for (int j = 0; j < 8; ++j) acc[r][j] = 0.f;
    const float4* Wv4 = reinterpret_cast<const float4*>(W);
    #pragma unroll 4
    for (int k = 0; k < KDIM; ++k) {
        const float4 w0 = Wv4[k * (NDIM / 4) + tid];
        const float4 w1 = Wv4[k * (NDIM / 4) + 256 + tid];
        #pragma unroll
        for (int r = 0; r < 8; ++r) {
            const float xv = xs[r][k];
            acc[r][0] = fmaf(xv, w0.x, acc[r][0]);
            acc[r][1] = fmaf(xv, w0.y, acc[r][1]);
            acc[r][2] = fmaf(xv, w0.z, acc[r][2]);
            acc[r][3] = fmaf(xv, w0.w, acc[r][3]);
            acc[r][4] = fmaf(xv, w1.x, acc[r][4]);
            acc[r][5] = fmaf(xv, w1.y, acc[r][5]);
            acc[r][6] = fmaf(xv, w1.z, acc[r][6]);
            acc[r][7] = fmaf(xv, w1.w, acc[r][7]);
        }
    }
    const float4* pmv = reinterpret_cast<const float4*>(pm);
    #pragma unroll
    for (int half = 0; half < 2; ++half) {
        __syncthreads();
        #pragma unroll
        for (int rr = 0; rr < 4; ++rr) {
            const int r = half * 4 + rr;
            const long rowbase4 = (r0 + r) * (NDIM / 4);
            const float4 m0 = pmv[rowbase4 + tid];
            const float4 m1 = pmv[rowbase4 + 256 + tid];
            float4 z0, z1;
            z0.x = acc[r][0] * m0.x; z0.y = acc[r][1] * m0.y;
            z0.z = acc[r][2] * m0.z; z0.w = acc[r][3] * m0.w;
            z1.x = acc[r][4] * m1.x; z1.y = acc[r][5] * m1.y;
            z1.z = acc[r][6] * m1.z; z1.w = acc[r][7] * m1.w;
            float4* zr = reinterpret_cast<float4*>(&zsf[rr][0]);
            zr[tid] = z0; zr[256 + tid] = z1;
        }
        __syncthreads();
        float zvv[32];
        const float4* zr = reinterpret_cast<const float4*>(&zsf[wv][0]);
        #pragma unroll
        for (int cc = 0; cc < 8; ++cc) {
            const float4 v = zr[cc * 64 + lane];
            zvv[cc * 4 + 0] = v.x; zvv[cc * 4 + 1] = v.y;
            zvv[cc * 4 + 2] = v.z; zvv[cc * 4 + 3] = v.w;
        }
        float s = 0.f;
        #pragma unroll
        for (int i = 0; i < 32; ++i) s += zvv[i];
        s = wave_sum(s);
        float tau = (s - 1.f) / 2048.f;
        float cprev = 2048.f;
        for (int itf = 0; itf < 64; ++itf) {
            float ps = 0.f, pc = 0.f;
            #pragma unroll
            for (int i = 0; i < 32; ++i)
                if (zvv[i] > tau) { ps += zvv[i]; pc += 1.f; }
            ps = wave_sum(ps);
            pc = wave_sum(pc);
            tau = (ps - 1.f) / pc;
            if (pc == cprev) break;
            cprev = pc;
        }
        float4* orow = reinterpret_cast<float4*>(out + (r0 + half * 4 + wv) * NDIM);
        #pragma unroll
        for (int cc = 0; cc < 8; ++cc) {
            float4 v;
            v.x = fmaxf(zvv[cc * 4 + 0] - tau, 0.f);
            v.y = fmaxf(zvv[cc * 4 + 1] - tau, 0.f);
            v.z = fmaxf(zvv[cc * 4 + 2] - tau, 0.f);
            v.w = fmaxf(zvv[cc * 4 + 3] - tau, 0.f);
            orow[cc * 64 + lane] = v;
        }
    }
}

extern "C" void kernel_launch(void* const* d_in, const int* in_sizes, int n_in,
                              void* d_out, int out_size, void* d_ws, size_t ws_size,
                              hipStream_t stream) {
    const float* x  = (const float*)d_in[0];   // [32768, 128]
    const float* pm = (const float*)d_in[1];   // [32768, 2048]
    const float* W  = (const float*)d_in[2];   // [128, 2048]
    float* out = (float*)d_out;

    const size_t szA = (size_t)BATCH * KDIM * sizeof(ushort);   // 8 MB each
    const size_t szB = (size_t)KDIM * NDIM * sizeof(ushort);    // 512 KB
    const size_t need = 2 * szA + szB;

    if (ws_size >= need) {
        char* base = (char*)d_ws;
        ushort* Ah = (ushort*)(base);
        ushort* Al = (ushort*)(base + szA);
        ushort* Bh = (ushort*)(base + 2 * szA);

        conv_x_kernel<<<(BATCH * KDIM) / 256, 256, 0, stream>>>(x, Ah, Al);
        conv_w_kernel<<<(KDIM * NDIM) / 256, 256, 0, stream>>>(W, Bh);
        mfma_sparsemax_persistent<<<GRID, 512, PMLDS_BYTES, stream>>>(Ah, Al, Bh, pm, out);
    } else {
        fused_sparsemax_fallback<<<BATCH / 8, 256, 0, stream>>>(x, pm, W, out);
    }
}

// Round 16
// 203.748 us; speedup vs baseline: 1.3623x; 1.3623x over previous
//
#include <hip/hip_runtime.h>
#include <hip/hip_bf16.h>

constexpr int BATCH = 32768;
constexpr int KDIM  = 128;    // IN_F
constexpr int NDIM  = 2048;   // OUT_F

using f32x4  = __attribute__((ext_vector_type(4))) float;
using bf16x8 = __attribute__((ext_vector_type(8))) short;

// ---------------------------------------------------------------------------
// Fragment order for mfma_f32_16x16x32_bf16 (verified R2/R3):
//   A (MxK): lane l holds m = l&15,  k(j) = 4*(l>>4) + (j&3) + 16*(j>>2)
//   B (KxN): lane l holds n = l&15,  same k(j)
//   D:       lane l holds col = l&15, row = (l>>4)*4 + reg
// 2-term split: z = (x_hi + x_lo) @ W_hi  (absmax ~8e-3 < 2e-2 threshold)
//
// R16 = R8 (210us champion: z->LDS, wave-owns-row, in-reg Michelot) + phase
// decorrelation. R8's 1.9TB/s (30% HBM) is lockstep: co-resident blocks hit
// their HBM phases (pm gate, out store) simultaneously, GEMM phases (L2-only)
// simultaneously. Fixes:
//  1) chunk-order stagger by blockIdx bit 8: partner blocks process chunks in
//     opposite order -> their HBM phases interleave with partner's compute.
//  2) pm prefetch for the first-processed chunk at kernel ENTRY (flies under
//     A-loads + whole GEMM); second chunk's pm issued right after the first
//     gather (flies under Michelot + store + scatter).
// R15 lesson: persistent + global_load_lds staging = +300MB mystery traffic;
// abandoned. R13: NT stores = +170MB write amplification; plain stores only.
// ---------------------------------------------------------------------------

__device__ inline void split_bf16(float v, ushort& hi, ushort& lo) {
    __hip_bfloat16 h = __float2bfloat16(v);
    float r = v - __bfloat162float(h);
    __hip_bfloat16 l = __float2bfloat16(r);
    hi = *reinterpret_cast<ushort*>(&h);
    lo = *reinterpret_cast<ushort*>(&l);
}

// W [128][2048] -> Bh[nt=128][kk=4][lane=64][j=8]  (hi only)
__global__ __launch_bounds__(256)
void conv_w_kernel(const float* __restrict__ W, ushort* __restrict__ Bh) {
    int id = blockIdx.x * 256 + threadIdx.x;      // 0 .. 262143
    int j  = id & 7;
    int l  = (id >> 3) & 63;
    int kk = (id >> 9) & 3;
    int nt = id >> 11;
    int k  = kk * 32 + 4 * (l >> 4) + (j & 3) + 16 * (j >> 2);
    int n  = nt * 16 + (l & 15);
    __hip_bfloat16 h = __float2bfloat16(W[k * NDIM + n]);
    Bh[id] = *reinterpret_cast<ushort*>(&h);
}

// x [32768][128] -> A{h,l}[rt=2048][kk=4][lane=64][j=8]
__global__ __launch_bounds__(256)
void conv_x_kernel(const float* __restrict__ x,
                   ushort* __restrict__ Ah, ushort* __restrict__ Al) {
    int id = blockIdx.x * 256 + threadIdx.x;      // 0 .. 4194303
    int j  = id & 7;
    int l  = (id >> 3) & 63;
    int kk = (id >> 9) & 3;
    int rt = id >> 11;
    int k  = kk * 32 + 4 * (l >> 4) + (j & 3) + 16 * (j >> 2);
    int m  = rt * 16 + (l & 15);
    ushort hi, lo;
    split_bf16(x[m * KDIM + k], hi, lo);
    Ah[id] = hi; Al[id] = lo;
}

// ---------------------------------------------------------------------------
// Main: grid 2048, 512 thr (8 waves), 16 rows x 2048 cols per block.
// GEMM (normal orientation): wave q -> col tiles q*16+t; acc[t][r] =
//   z[row g*4+r][col q*256+t*16+(l&15)], acc in AGPRs.
// Two 8-row chunks through 64KB LDS (order staggered by block); wave q owns
// row (c*8+q): coalesced pm/out, in-register wave-local Michelot.
// ---------------------------------------------------------------------------
constexpr int GRID = BATCH / 16;                // 2048
constexpr int LDS_BYTES = 8 * NDIM * 4;         // 65536 B

__global__ __launch_bounds__(512, 2)
void mfma_sparsemax_kernel(const ushort* __restrict__ Ah, const ushort* __restrict__ Al,
                           const ushort* __restrict__ Bh,
                           const float* __restrict__ pm, float* __restrict__ out) {
    extern __shared__ float zs[];               // [8][2048]

    const int tid = threadIdx.x;
    const int l   = tid & 63;
    const int q   = tid >> 6;                   // wave id 0..7
    const int g   = l >> 4;
    const int rt  = blockIdx.x;                 // row-tile (16 rows)
    const int c0  = (blockIdx.x >> 8) & 1;      // chunk-order stagger bit

    const bf16x8* A8h = reinterpret_cast<const bf16x8*>(Ah);
    const bf16x8* A8l = reinterpret_cast<const bf16x8*>(Al);
    const bf16x8* B8h = reinterpret_cast<const bf16x8*>(Bh);

    // ---- entry prefetch: pm row for the FIRST-processed chunk (c0*8+q) ----
    f32x4 pmv[8];
    {
        const f32x4* pmrow = reinterpret_cast<const f32x4*>(
            pm + ((long)rt * 16 + c0 * 8 + q) * NDIM);
        #pragma unroll
        for (int j = 0; j < 8; ++j) pmv[j] = pmrow[j * 64 + l];
    }

    // ---- A fragments (16 rows) ----
    bf16x8 ah[4], al[4];
    #pragma unroll
    for (int kk = 0; kk < 4; ++kk) {
        ah[kk] = A8h[(rt * 4 + kk) * 64 + l];
        al[kk] = A8l[(rt * 4 + kk) * 64 + l];
    }

    // ---- GEMM: wave q -> col tiles nt = q*16+t (pm loads fly underneath) ----
    f32x4 acc[16];
    #pragma unroll
    for (int t = 0; t < 16; ++t) {
        const int nt = q * 16 + t;
        f32x4 c = {0.f, 0.f, 0.f, 0.f};
        #pragma unroll
        for (int kk = 0; kk < 4; ++kk) {
            bf16x8 b = B8h[(nt * 4 + kk) * 64 + l];
            c = __builtin_amdgcn_mfma_f32_16x16x32_bf16(ah[kk], b, c, 0, 0, 0);
            c = __builtin_amdgcn_mfma_f32_16x16x32_bf16(al[kk], b, c, 0, 0, 0);
        }
        acc[t] = c;
    }

    // ---- two 8-row chunks through LDS, block-staggered order ----
    #pragma unroll
    for (int cc = 0; cc < 2; ++cc) {
        const int c = cc ^ c0;                  // this block's chunk order
        __syncthreads();                        // zs free (prev chunk consumed)

        // scatter: g-groups 2c,2c+1 hold chunk c's rows (local (g&1)*4+r)
        if ((g >> 1) == c) {
            #pragma unroll
            for (int t = 0; t < 16; ++t)
                #pragma unroll
                for (int r = 0; r < 4; ++r)
                    zs[((g & 1) * 4 + r) * NDIM + q * 256 + t * 16 + (l & 15)] = acc[t][r];
        }

        __syncthreads();                        // zs ready

        // gather my row, gate by (prefetched) pm
        const long grow = (long)rt * 16 + c * 8 + q;
        const f32x4* zrow = reinterpret_cast<const f32x4*>(zs + q * NDIM);
        float zv[32];
        #pragma unroll
        for (int j = 0; j < 8; ++j) {
            f32x4 v = zrow[j * 64 + l];
            zv[j * 4 + 0] = v.x * pmv[j].x;
            zv[j * 4 + 1] = v.y * pmv[j].y;
            zv[j * 4 + 2] = v.z * pmv[j].z;
            zv[j * 4 + 3] = v.w * pmv[j].w;
        }

        // issue NEXT chunk's pm loads now (fly under Michelot + store + scatter)
        if (cc == 0) {
            const f32x4* pmrow2 = reinterpret_cast<const f32x4*>(
                pm + ((long)rt * 16 + (c ^ 1) * 8 + q) * NDIM);
            #pragma unroll
            for (int j = 0; j < 8; ++j) pmv[j] = pmrow2[j * 64 + l];
        }

        // Michelot sparsemax, tau0 = max(rowmax-1, (sum-1)/N); in-register
        float s = 0.f, m = zv[0];
        #pragma unroll
        for (int i = 0; i < 32; ++i) { s += zv[i]; m = fmaxf(m, zv[i]); }
        #pragma unroll
        for (int off = 32; off > 0; off >>= 1) {
            s += __shfl_xor(s, off, 64);
            m = fmaxf(m, __shfl_xor(m, off, 64));
        }
        float tau = fmaxf(m - 1.f, (s - 1.f) * (1.f / 2048.f));
        float cprev = -1.f;
        for (int itr = 0; itr < 64; ++itr) {
            float ps = 0.f, pc = 0.f;
            #pragma unroll
            for (int i = 0; i < 32; ++i) {
                bool a = zv[i] > tau;
                ps += a ? zv[i] : 0.f;
                pc += a ? 1.f : 0.f;
            }
            #pragma unroll
            for (int off = 32; off > 0; off >>= 1) {
                ps += __shfl_xor(ps, off, 64);
                pc += __shfl_xor(pc, off, 64);
            }
            tau = (ps - 1.f) / pc;              // pc >= 1 always
            if (pc == cprev) break;             // stable count = fixpoint
            cprev = pc;
        }

        // out = max(z - tau, 0), coalesced f32x4
        f32x4* orow = reinterpret_cast<f32x4*>(out + grow * NDIM);
        #pragma unroll
        for (int j = 0; j < 8; ++j) {
            f32x4 v;
            v.x = fmaxf(zv[j * 4 + 0] - tau, 0.f);
            v.y = fmaxf(zv[j * 4 + 1] - tau, 0.f);
            v.z = fmaxf(zv[j * 4 + 2] - tau, 0.f);
            v.w = fmaxf(zv[j * 4 + 3] - tau, 0.f);
            orow[j * 64 + l] = v;
        }
    }
}

// ---------------------------------------------------------------------------
// Fallback (R1 kernel) if d_ws too small.
// ---------------------------------------------------------------------------
__device__ inline float wave_sum(float v) {
    #pragma unroll
    for (int off = 32; off > 0; off >>= 1) v += __shfl_xor(v, off, 64);
    return v;
}

__global__ __launch_bounds__(256)
void fused_sparsemax_fallback(const float* __restrict__ x,
                              const float* __restrict__ pm,
                              const float* __restrict__ W,
                              float* __restrict__ out) {
    __shared__ float xs[8][KDIM];
    __shared__ float zsf[4][NDIM];
    const int tid  = threadIdx.x;
    const int lane = tid & 63;
    const int wv   = tid >> 6;
    const long r0  = (long)blockIdx.x * 8;
    {
        const float4* src = reinterpret_cast<const float4*>(x + r0 * KDIM);
        reinterpret_cast<float4*>(&xs[0][0])[tid] = src[tid];
    }
    __syncthreads();
    float acc[8][8];
    #pragma unroll
    for (int r = 0; r < 8; ++r)
        #pragma unroll
        for (int j = 0; j < 8; ++j) acc[r][j] = 0.f;
    const float4* Wv4 = reinterpret_cast<const float4*>(W);
    #pragma unroll 4
    for (int k = 0; k < KDIM; ++k) {
        const float4 w0 = Wv4[k * (NDIM / 4) + tid];
        const float4 w1 = Wv4[k * (NDIM / 4) + 256 + tid];
        #pragma unroll
        for (int r = 0; r < 8; ++r) {
            const float xv = xs[r][k];
            acc[r][0] = fmaf(xv, w0.x, acc[r][0]);
            acc[r][1] = fmaf(xv, w0.y, acc[r][1]);
            acc[r][2] = fmaf(xv, w0.z, acc[r][2]);
            acc[r][3] = fmaf(xv, w0.w, acc[r][3]);
            acc[r][4] = fmaf(xv, w1.x, acc[r][4]);
            acc[r][5] = fmaf(xv, w1.y, acc[r][5]);
            acc[r][6] = fmaf(xv, w1.z, acc[r][6]);
            acc[r][7] = fmaf(xv, w1.w, acc[r][7]);
        }
    }
    const float4* pmv = reinterpret_cast<const float4*>(pm);
    #pragma unroll
    for (int half = 0; half < 2; ++half) {
        __syncthreads();
        #pragma unroll
        for (int rr = 0; rr < 4; ++rr) {
            const int r = half * 4 + rr;
            const long rowbase4 = (r0 + r) * (NDIM / 4);
            const float4 m0 = pmv[rowbase4 + tid];
            const float4 m1 = pmv[rowbase4 + 256 + tid];
            float4 z0, z1;
            z0.x = acc[r][0] * m0.x; z0.y = acc[r][1] * m0.y;
            z0.z = acc[r][2] * m0.z; z0.w = acc[r][3] * m0.w;
            z1.x = acc[r][4] * m1.x; z1.y = acc[r][5] * m1.y;
            z1.z = acc[r][6] * m1.z; z1.w = acc[r][7] * m1.w;
            float4* zr = reinterpret_cast<float4*>(&zsf[rr][0]);
            zr[tid] = z0; zr[256 + tid] = z1;
        }
        __syncthreads();
        float zvv[32];
        const float4* zr = reinterpret_cast<const float4*>(&zsf[wv][0]);
        #pragma unroll
        for (int cc = 0; cc < 8; ++cc) {
            const float4 v = zr[cc * 64 + lane];
            zvv[cc * 4 + 0] = v.x; zvv[cc * 4 + 1] = v.y;
            zvv[cc * 4 + 2] = v.z; zvv[cc * 4 + 3] = v.w;
        }
        float s = 0.f;
        #pragma unroll
        for (int i = 0; i < 32; ++i) s += zvv[i];
        s = wave_sum(s);
        float tau = (s - 1.f) / 2048.f;
        float cprev = 2048.f;
        for (int itf = 0; itf < 64; ++itf) {
            float ps = 0.f, pc = 0.f;
            #pragma unroll
            for (int i = 0; i < 32; ++i)
                if (zvv[i] > tau) { ps += zvv[i]; pc += 1.f; }
            ps = wave_sum(ps);
            pc = wave_sum(pc);
            tau = (ps - 1.f) / pc;
            if (pc == cprev) break;
            cprev = pc;
        }
        float4* orow = reinterpret_cast<float4*>(out + (r0 + half * 4 + wv) * NDIM);
        #pragma unroll
        for (int cc = 0; cc < 8; ++cc) {
            float4 v;
            v.x = fmaxf(zvv[cc * 4 + 0] - tau, 0.f);
            v.y = fmaxf(zvv[cc * 4 + 1] - tau, 0.f);
            v.z = fmaxf(zvv[cc * 4 + 2] - tau, 0.f);
            v.w = fmaxf(zvv[cc * 4 + 3] - tau, 0.f);
            orow[cc * 64 + lane] = v;
        }
    }
}

extern "C" void kernel_launch(void* const* d_in, const int* in_sizes, int n_in,
                              void* d_out, int out_size, void* d_ws, size_t ws_size,
                              hipStream_t stream) {
    const float* x  = (const float*)d_in[0];   // [32768, 128]
    const float* pm = (const float*)d_in[1];   // [32768, 2048]
    const float* W  = (const float*)d_in[2];   // [128, 2048]
    float* out = (float*)d_out;

    const size_t szA = (size_t)BATCH * KDIM * sizeof(ushort);   // 8 MB each
    const size_t szB = (size_t)KDIM * NDIM * sizeof(ushort);    // 512 KB
    const size_t need = 2 * szA + szB;

    if (ws_size >= need) {
        char* base = (char*)d_ws;
        ushort* Ah = (ushort*)(base);
        ushort* Al = (ushort*)(base + szA);
        ushort* Bh = (ushort*)(base + 2 * szA);

        conv_x_kernel<<<(BATCH * KDIM) / 256, 256, 0, stream>>>(x, Ah, Al);
        conv_w_kernel<<<(KDIM * NDIM) / 256, 256, 0, stream>>>(W, Bh);
        mfma_sparsemax_kernel<<<GRID, 512, LDS_BYTES, stream>>>(Ah, Al, Bh, pm, out);
    } else {
        fused_sparsemax_fallback<<<BATCH / 8, 256, 0, stream>>>(x, pm, W, out);
    }
}